// Round 2
// baseline (1082.308 us; speedup 1.0000x reference)
//
#include <hip/hip_runtime.h>
#include <math.h>

#define TOPK 8
#define NE   128      // experts
#define BT   64       // tokens per block
#define BK   32       // K tile
#define XPAD 36       // padded x_s row stride (floats)
#define MARGIN 4e-5f  // flag threshold on adjacent balancing-score gaps (ranks 1..9)

// ---------------- Pass 1: fp32 GEMM + sigmoid + top-8 + near-tie flagging ----------------
__global__ __launch_bounds__(256, 2) void router_pass1(
    const float* __restrict__ x,       // [T, H]
    const float* __restrict__ W,       // [E, H]
    const float* __restrict__ bias,    // [E]
    float* __restrict__ out_w,         // [T, 8]
    float* __restrict__ out_i,         // [T, 8] (indices as float)
    int* __restrict__ cnt,             // flag counter
    int* __restrict__ flags,           // flagged token ids
    int T, int H) {
  __shared__ float x_s[BT * XPAD];     // [token][k] padded
  __shared__ float w_s[BK * NE];       // [k][expert] transposed

  const int tid = threadIdx.x;
  const int t0  = blockIdx.x * BT;
  const int tx  = tid & 15;            // expert group: experts tx*8 .. tx*8+7
  const int ty  = tid >> 4;            // token group: tokens ty*4 .. ty*4+3
  const int q   = tid & 7;             // k-quad for staging
  const int sr  = tid >> 3;            // staging row 0..31

  float biasr[8];
  {
    const float4 b0 = *(const float4*)(bias + tx * 8);
    const float4 b1 = *(const float4*)(bias + tx * 8 + 4);
    biasr[0] = b0.x; biasr[1] = b0.y; biasr[2] = b0.z; biasr[3] = b0.w;
    biasr[4] = b1.x; biasr[5] = b1.y; biasr[6] = b1.z; biasr[7] = b1.w;
  }

  float acc[4][8];
#pragma unroll
  for (int i = 0; i < 4; ++i)
#pragma unroll
    for (int j = 0; j < 8; ++j) acc[i][j] = 0.f;

  for (int k0 = 0; k0 < H; k0 += BK) {
    __syncthreads();
    {
      const float4 v0 = *(const float4*)(x + (size_t)(t0 + sr) * H + k0 + q * 4);
      const float4 v1 = *(const float4*)(x + (size_t)(t0 + sr + 32) * H + k0 + q * 4);
      *(float4*)(x_s + sr * XPAD + q * 4)        = v0;
      *(float4*)(x_s + (sr + 32) * XPAD + q * 4) = v1;
    }
    {
      const int eg = sr;
      const float* wp = W + (size_t)(eg * 4) * H + k0 + q * 4;
      const float4 r0 = *(const float4*)(wp);
      const float4 r1 = *(const float4*)(wp + H);
      const float4 r2 = *(const float4*)(wp + 2 * (size_t)H);
      const float4 r3 = *(const float4*)(wp + 3 * (size_t)H);
      *(float4*)(w_s + (q * 4 + 0) * NE + eg * 4) = make_float4(r0.x, r1.x, r2.x, r3.x);
      *(float4*)(w_s + (q * 4 + 1) * NE + eg * 4) = make_float4(r0.y, r1.y, r2.y, r3.y);
      *(float4*)(w_s + (q * 4 + 2) * NE + eg * 4) = make_float4(r0.z, r1.z, r2.z, r3.z);
      *(float4*)(w_s + (q * 4 + 3) * NE + eg * 4) = make_float4(r0.w, r1.w, r2.w, r3.w);
    }
    __syncthreads();

#pragma unroll
    for (int k4 = 0; k4 < BK / 4; ++k4) {
      float4 xv[4];
#pragma unroll
      for (int i = 0; i < 4; ++i)
        xv[i] = *(const float4*)(x_s + (ty * 4 + i) * XPAD + k4 * 4);

#define FMA_K(kk, comp)                                                      \
      {                                                                      \
        const float4 w0 = *(const float4*)(w_s + (k4 * 4 + kk) * NE + tx * 8);     \
        const float4 w1 = *(const float4*)(w_s + (k4 * 4 + kk) * NE + tx * 8 + 4); \
        _Pragma("unroll")                                                    \
        for (int i = 0; i < 4; ++i) {                                        \
          const float xs = xv[i].comp;                                       \
          acc[i][0] = fmaf(xs, w0.x, acc[i][0]);                             \
          acc[i][1] = fmaf(xs, w0.y, acc[i][1]);                             \
          acc[i][2] = fmaf(xs, w0.z, acc[i][2]);                             \
          acc[i][3] = fmaf(xs, w0.w, acc[i][3]);                             \
          acc[i][4] = fmaf(xs, w1.x, acc[i][4]);                             \
          acc[i][5] = fmaf(xs, w1.y, acc[i][5]);                             \
          acc[i][6] = fmaf(xs, w1.z, acc[i][6]);                             \
          acc[i][7] = fmaf(xs, w1.w, acc[i][7]);                             \
        }                                                                    \
      }
      FMA_K(0, x)
      FMA_K(1, y)
      FMA_K(2, z)
      FMA_K(3, w)
#undef FMA_K
    }
  }

  const int lane  = tid & 63;
  const int gbase = lane & 48;

#pragma unroll
  for (int i = 0; i < 4; ++i) {
    float sc[8], bal[8];
#pragma unroll
    for (int j = 0; j < 8; ++j) {
      const float s = 1.f / (1.f + expf(-acc[i][j]));
      sc[j]  = s;
      bal[j] = s + biasr[j];
    }

    float myw[TOPK];
    int   myid[TOPK];
    float prev = 0.f;
    int   flagged = 0;
#pragma unroll
    for (int r = 0; r < TOPK + 1; ++r) {
      float bv = bal[0];
      int   bi = tx * 8;
#pragma unroll
      for (int j = 1; j < 8; ++j)
        if (bal[j] > bv) { bv = bal[j]; bi = tx * 8 + j; }
#pragma unroll
      for (int m = 1; m <= 8; m <<= 1) {
        const float ov = __shfl_xor(bv, m);
        const int   oi = __shfl_xor(bi, m);
        if (ov > bv || (ov == bv && oi < bi)) { bv = ov; bi = oi; }
      }
      if (r > 0 && (prev - bv) < MARGIN) flagged = 1;
      prev = bv;
      if (r < TOPK) {
        const int jt = bi & 7;
        const int ls = bi >> 3;
        const float a0 = (jt & 1) ? sc[1] : sc[0];
        const float a1 = (jt & 1) ? sc[3] : sc[2];
        const float a2 = (jt & 1) ? sc[5] : sc[4];
        const float a3 = (jt & 1) ? sc[7] : sc[6];
        const float b0 = (jt & 2) ? a1 : a0;
        const float b1 = (jt & 2) ? a3 : a2;
        const float sv = (jt & 4) ? b1 : b0;
        const float sw = __shfl(sv, gbase | ls);
        myw[r]  = sw;
        myid[r] = bi;
#pragma unroll
        for (int j = 0; j < 8; ++j)
          if (ls == tx && j == jt) bal[j] = -INFINITY;
      }
    }

    if (tx == 0) {
      float den = 0.f;
#pragma unroll
      for (int r = 0; r < TOPK; ++r) den += fabsf(myw[r]);
      den = fmaxf(den, 1e-12f);
      const int t = t0 + ty * 4 + i;
#pragma unroll
      for (int r = 0; r < TOPK; ++r) {
        out_w[(size_t)t * TOPK + r] = myw[r] / den;
        out_i[(size_t)t * TOPK + r] = (float)myid[r];
      }
      if (flagged) {
        const int p = atomicAdd(cnt, 1);
        flags[p] = t;
      }
    }
  }
}

// ---------------- Pass 2: fp64 recompute of flagged tokens ----------------
__global__ __launch_bounds__(256) void router_pass2(
    const float* __restrict__ x, const float* __restrict__ W,
    const float* __restrict__ bias,
    float* __restrict__ out_w, float* __restrict__ out_i,
    const int* __restrict__ cnt, const int* __restrict__ flags, int H) {
  __shared__ float x_s[BT * XPAD];
  __shared__ float w_s[BK * NE];
  __shared__ int   tok_s[BT];

  const int count = cnt[0];
  const int base  = blockIdx.x * BT;
  if (base >= count) return;
  const int nt = min(BT, count - base);

  const int tid = threadIdx.x;
  const int tx  = tid & 15;
  const int ty  = tid >> 4;
  const int q   = tid & 7;
  const int sr  = tid >> 3;

  if (tid < BT) tok_s[tid] = flags[base + min(tid, nt - 1)];

  float biasr[8];
#pragma unroll
  for (int j = 0; j < 8; ++j) biasr[j] = bias[tx * 8 + j];

  double acc[4][8];
#pragma unroll
  for (int i = 0; i < 4; ++i)
#pragma unroll
    for (int j = 0; j < 8; ++j) acc[i][j] = 0.0;

  for (int k0 = 0; k0 < H; k0 += BK) {
    __syncthreads();
    {
      const int r0t = tok_s[sr];
      const int r1t = tok_s[sr + 32];
      const float4 v0 = *(const float4*)(x + (size_t)r0t * H + k0 + q * 4);
      const float4 v1 = *(const float4*)(x + (size_t)r1t * H + k0 + q * 4);
      *(float4*)(x_s + sr * XPAD + q * 4)        = v0;
      *(float4*)(x_s + (sr + 32) * XPAD + q * 4) = v1;
    }
    {
      const int eg = sr;
      const float* wp = W + (size_t)(eg * 4) * H + k0 + q * 4;
      const float4 r0 = *(const float4*)(wp);
      const float4 r1 = *(const float4*)(wp + H);
      const float4 r2 = *(const float4*)(wp + 2 * (size_t)H);
      const float4 r3 = *(const float4*)(wp + 3 * (size_t)H);
      *(float4*)(w_s + (q * 4 + 0) * NE + eg * 4) = make_float4(r0.x, r1.x, r2.x, r3.x);
      *(float4*)(w_s + (q * 4 + 1) * NE + eg * 4) = make_float4(r0.y, r1.y, r2.y, r3.y);
      *(float4*)(w_s + (q * 4 + 2) * NE + eg * 4) = make_float4(r0.z, r1.z, r2.z, r3.z);
      *(float4*)(w_s + (q * 4 + 3) * NE + eg * 4) = make_float4(r0.w, r1.w, r2.w, r3.w);
    }
    __syncthreads();

#pragma unroll
    for (int k4 = 0; k4 < BK / 4; ++k4) {
      float4 xv[4];
#pragma unroll
      for (int i = 0; i < 4; ++i)
        xv[i] = *(const float4*)(x_s + (ty * 4 + i) * XPAD + k4 * 4);
#pragma unroll
      for (int kk = 0; kk < 4; ++kk) {
        const float4 w0 = *(const float4*)(w_s + (k4 * 4 + kk) * NE + tx * 8);
        const float4 w1 = *(const float4*)(w_s + (k4 * 4 + kk) * NE + tx * 8 + 4);
        double wd[8];
        wd[0] = w0.x; wd[1] = w0.y; wd[2] = w0.z; wd[3] = w0.w;
        wd[4] = w1.x; wd[5] = w1.y; wd[6] = w1.z; wd[7] = w1.w;
#pragma unroll
        for (int i = 0; i < 4; ++i) {
          const double xs = (double)(((const float*)&xv[i])[kk]);
#pragma unroll
          for (int j = 0; j < 8; ++j) acc[i][j] = fma(xs, wd[j], acc[i][j]);
        }
      }
    }
  }

  const int lane  = tid & 63;
  const int gbase = lane & 48;

#pragma unroll
  for (int i = 0; i < 4; ++i) {
    const int slot = ty * 4 + i;
    double sc[8], bal[8];
#pragma unroll
    for (int j = 0; j < 8; ++j) {
      const double s = 1.0 / (1.0 + exp(-acc[i][j]));
      sc[j]  = s;
      bal[j] = s + (double)biasr[j];
    }

    double myw[TOPK];
    int    myid[TOPK];
#pragma unroll
    for (int r = 0; r < TOPK; ++r) {
      double bv = bal[0];
      int    bi = tx * 8;
#pragma unroll
      for (int j = 1; j < 8; ++j)
        if (bal[j] > bv) { bv = bal[j]; bi = tx * 8 + j; }
#pragma unroll
      for (int m = 1; m <= 8; m <<= 1) {
        const double ov = __shfl_xor(bv, m);
        const int    oi = __shfl_xor(bi, m);
        if (ov > bv || (ov == bv && oi < bi)) { bv = ov; bi = oi; }
      }
      const int jt = bi & 7;
      const int ls = bi >> 3;
      const double a0 = (jt & 1) ? sc[1] : sc[0];
      const double a1 = (jt & 1) ? sc[3] : sc[2];
      const double a2 = (jt & 1) ? sc[5] : sc[4];
      const double a3 = (jt & 1) ? sc[7] : sc[6];
      const double b0 = (jt & 2) ? a1 : a0;
      const double b1 = (jt & 2) ? a3 : a2;
      const double sv = (jt & 4) ? b1 : b0;
      const double sw = __shfl(sv, gbase | ls);
      myw[r]  = sw;
      myid[r] = bi;
#pragma unroll
      for (int j = 0; j < 8; ++j)
        if (ls == tx && j == jt) bal[j] = -INFINITY;
    }

    if (tx == 0 && slot < nt) {
      double den = 0.0;
#pragma unroll
      for (int r = 0; r < TOPK; ++r) den += fabs(myw[r]);
      den = fmax(den, 1e-12);
      const int t = tok_s[slot];
#pragma unroll
      for (int r = 0; r < TOPK; ++r) {
        out_w[(size_t)t * TOPK + r] = (float)(myw[r] / den);
        out_i[(size_t)t * TOPK + r] = (float)myid[r];
      }
    }
  }
}

extern "C" void kernel_launch(void* const* d_in, const int* in_sizes, int n_in,
                              void* d_out, int out_size, void* d_ws, size_t ws_size,
                              hipStream_t stream) {
  const float* x    = (const float*)d_in[0];
  const float* W    = (const float*)d_in[1];
  const float* bias = (const float*)d_in[2];
  const int E = in_sizes[2];            // 128
  const int H = in_sizes[1] / E;        // 4096
  const int T = in_sizes[0] / H;        // 32768
  (void)E; (void)n_in; (void)ws_size; (void)out_size;

  float* out_w = (float*)d_out;
  float* out_i = out_w + (size_t)T * TOPK;

  int* cnt   = (int*)d_ws;
  int* flags = (int*)d_ws + 4;          // 16-byte offset

  hipMemsetAsync(d_ws, 0, 16, stream);
  router_pass1<<<dim3(T / BT), dim3(256), 0, stream>>>(x, W, bias, out_w, out_i, cnt, flags, T, H);
  router_pass2<<<dim3(T / BT), dim3(256), 0, stream>>>(x, W, bias, out_w, out_i, cnt, flags, H);
}